// Round 6
// baseline (602.065 us; speedup 1.0000x reference)
//
#include <hip/hip_runtime.h>
#include <hip/hip_bf16.h>

typedef __hip_bfloat16 bf16;
typedef __attribute__((ext_vector_type(4))) short short4v;
typedef __attribute__((ext_vector_type(8))) short short8;
typedef __attribute__((ext_vector_type(4))) float f32x4;

#define NB 4
#define NT 1024
#define NE 2048
#define NH 32
#define ND 64
#define NBH (NB*NH)

__device__ __forceinline__ short bf16bits(float x) {
    bf16 h = __float2bfloat16(x);
    return *reinterpret_cast<short*>(&h);
}
__device__ __forceinline__ float bitsbf16(short s) {
    bf16 h = *reinterpret_cast<bf16*>(&s);
    return __bfloat162float(h);
}

// async global->LDS, 16B per lane; LDS dest = wave-uniform base + lane*16.
__device__ __forceinline__ void gll16(const bf16* g, bf16* l) {
    __builtin_amdgcn_global_load_lds(
        (const __attribute__((address_space(1))) unsigned int*)g,
        (__attribute__((address_space(3))) unsigned int*)l, 16, 0, 0);
}

// Storage-dtype probe (flag=1 -> inputs are fp32). See round-2 notes.
__global__ void detect_dtype(const unsigned short* __restrict__ w, int* __restrict__ flag) {
    int l = threadIdx.x;
    int big = 0;
    for (int i = l; i < 512; i += 64) {
        unsigned e = (w[i] >> 7) & 0xFFu;
        if (e >= 0x88u) big = 1;
    }
    unsigned long long m = __ballot(big != 0);
    if (l == 0) *flag = (m != 0ULL) ? 1 : 0;
}

// One kernel converting hs + 4 weights to bf16. 2048 elems per block.
__global__ __launch_bounds__(256) void conv_all(
    const void* __restrict__ hs, const void* __restrict__ wq, const void* __restrict__ wk,
    const void* __restrict__ wv, const void* __restrict__ wo,
    bf16* __restrict__ dhs, bf16* __restrict__ dwq, bf16* __restrict__ dwk,
    bf16* __restrict__ dwv, bf16* __restrict__ dwo, const int* __restrict__ flagp)
{
    const bool f32 = (*flagp != 0);
    int bid = blockIdx.x;
    const void* src; bf16* dst; size_t blk;
    if (bid < 4096)      { src = hs; dst = dhs; blk = bid; }
    else {
        int r = (bid - 4096) >> 11, o = (bid - 4096) & 2047;
        blk = o;
        src = r == 0 ? wq : (r == 1 ? wk : (r == 2 ? wv : wo));
        dst = r == 0 ? dwq : (r == 1 ? dwk : (r == 2 ? dwv : dwo));
    }
    size_t i = (blk * 256 + threadIdx.x) * 8;
    if (f32) {
        const float* s = (const float*)src + i;
        f32x4 a = *(const f32x4*)s;
        f32x4 b = *(const f32x4*)(s + 4);
        short8 r8;
        r8[0] = bf16bits(a[0]); r8[1] = bf16bits(a[1]);
        r8[2] = bf16bits(a[2]); r8[3] = bf16bits(a[3]);
        r8[4] = bf16bits(b[0]); r8[5] = bf16bits(b[1]);
        r8[6] = bf16bits(b[2]); r8[7] = bf16bits(b[3]);
        *(short8*)(dst + i) = r8;
    } else {
        *(short8*)(dst + i) = *(const short8*)((const bf16*)src + i);
    }
}

// ---------------- fused QKV GEMM: BK=64, swizzled A-LDS, B direct from global ----------
// grid.z: 0=Q (fake-quant fused, out [B,H,T,D]), 1=K (abs-max stats, out [B,H,T,D]),
//         2=V (min/max stats, out [B,H,D,T]).
// As[128][64] bf16, XOR-swizzled: LDS[row][slot] = global[row][slot ^ (row&7)] (16B colblks).
// A-frag read for row R, colblk g -> slot g^(R&7): start banks slot*4 spread over all 32,
// 2 lanes/bank (lr, lr+8) = conflict-free. B-frags are plain VGPR loads (W rows L1/L2-hot),
// issued before the barrier so they drain with the staging DMA.
__global__ __launch_bounds__(256) void gemm_qkv(
    const bf16* __restrict__ A,
    const bf16* __restrict__ Wq, const bf16* __restrict__ Wk, const bf16* __restrict__ Wv,
    const void* __restrict__ bq, const void* __restrict__ bk, const void* __restrict__ bv,
    bf16* __restrict__ Qb, bf16* __restrict__ Kb, bf16* __restrict__ Vt,
    const int* __restrict__ flagp,
    int* __restrict__ sKb, int* __restrict__ vMx, int* __restrict__ vNg)
{
    const int K = NE, z = blockIdx.z;
    const bf16* W = z == 0 ? Wq : (z == 1 ? Wk : Wv);
    const void* bias = z == 0 ? bq : (z == 1 ? bk : bv);
    const float scale = z == 0 ? 0.125f : 1.0f;

    __shared__ __align__(16) bf16 As[128 * 64];
    int tid = threadIdx.x;
    int w = tid >> 6, l = tid & 63;
    int lr = l & 15, quad = l >> 4;
    int mBase = blockIdx.y * 128, nBase = blockIdx.x * 128;
    int mw = (w >> 1) * 64, nw = (w & 1) * 64;
    f32x4 acc[4][4] = {};

    int srow = w * 32 + (l >> 3);
    int scol = ((l & 7) ^ ((l >> 3) & 7)) * 8;      // swizzled source colblk
    const bf16* Ag = A + (size_t)(mBase + srow) * K + scol;
    bf16* AsW = As + (w * 32) * 64;

    const bf16* Wp = W + (size_t)(nBase + nw + lr) * K + quad * 8;

    for (int k0 = 0; k0 < K; k0 += 64) {
        #pragma unroll
        for (int c = 0; c < 4; c++)
            gll16(Ag + (size_t)(c * 8) * K + k0, AsW + (c * 8) * 64);
        short8 bfr[4][2];
        #pragma unroll
        for (int j = 0; j < 4; j++)
            #pragma unroll
            for (int h = 0; h < 2; h++)
                bfr[j][h] = *(const short8*)(Wp + (size_t)(j * 16) * K + k0 + h * 32);
        __syncthreads();                              // drains DMA + B loads
        #pragma unroll
        for (int i = 0; i < 4; i++) {
            #pragma unroll
            for (int h = 0; h < 2; h++) {
                short8 a8 = *(const short8*)(
                    As + (mw + i * 16 + lr) * 64 + (((h * 4 + quad) ^ (lr & 7)) * 8));
                #pragma unroll
                for (int j = 0; j < 4; j++)
                    acc[i][j] = __builtin_amdgcn_mfma_f32_16x16x32_bf16(
                        a8, bfr[j][h], acc[i][j], 0, 0, 0);
            }
        }
        __syncthreads();
    }

    const bool f32 = (*flagp != 0);
    float bv4[4];
    #pragma unroll
    for (int j = 0; j < 4; j++) {
        int n = nBase + nw + j * 16 + lr;
        bv4[j] = f32 ? ((const float*)bias)[n] : bitsbf16(((const short*)bias)[n]);
    }
    float colA[4] = {0.f, 0.f, 0.f, 0.f};
    float colB[4] = {0.f, 0.f, 0.f, 0.f};

    #pragma unroll
    for (int i = 0; i < 4; i++) {
        float v[4][4];
        #pragma unroll
        for (int j = 0; j < 4; j++)
            #pragma unroll
            for (int r = 0; r < 4; r++)
                v[j][r] = (acc[i][j][r] + bv4[j]) * scale;

        if (z == 0) {
            #pragma unroll
            for (int r = 0; r < 4; r++) {
                float mx = 0.f, mn = 0.f;
                #pragma unroll
                for (int j = 0; j < 4; j++) { mx = fmaxf(mx, v[j][r]); mn = fminf(mn, v[j][r]); }
                #pragma unroll
                for (int off = 1; off < 16; off <<= 1) {
                    mx = fmaxf(mx, __shfl_xor(mx, off));
                    mn = fminf(mn, __shfl_xor(mn, off));
                }
                float sc = (mx - mn) * (1.f / 255.f);
                if (sc <= 0.f) sc = 1.f;
                float zq = rintf(-mn / sc);
                #pragma unroll
                for (int j = 0; j < 4; j++) {
                    float q = fminf(fmaxf(rintf(v[j][r] / sc) + zq, 0.f), 255.f);
                    v[j][r] = sc * (q - zq);
                }
            }
        } else if (z == 1) {
            #pragma unroll
            for (int j = 0; j < 4; j++)
                #pragma unroll
                for (int r = 0; r < 4; r++)
                    colA[j] = fmaxf(colA[j], fabsf(v[j][r]));
        } else {
            #pragma unroll
            for (int j = 0; j < 4; j++)
                #pragma unroll
                for (int r = 0; r < 4; r++) {
                    colA[j] = fmaxf(colA[j], v[j][r]);
                    colB[j] = fmaxf(colB[j], -v[j][r]);
                }
        }

        #pragma unroll
        for (int j = 0; j < 4; j++) {
            int n = nBase + nw + j * 16 + lr;
            int h = n >> 6, d = n & (ND - 1);
            #pragma unroll
            for (int r = 0; r < 4; r++) {
                int m = mBase + mw + i * 16 + quad * 4 + r;
                int b = m >> 10, t = m & (NT - 1);
                if (z == 0)
                    Qb[(((size_t)(b * NH + h)) * NT + t) * ND + d] = (bf16)v[j][r];
                else if (z == 1)
                    Kb[(((size_t)(b * NH + h)) * NT + t) * ND + d] = (bf16)v[j][r];
                else
                    Vt[(((size_t)(b * NH + h)) * ND + d) * NT + t] = (bf16)v[j][r];
            }
        }
    }

    if (z >= 1) {
        int b = mBase >> 10;
        #pragma unroll
        for (int j = 0; j < 4; j++) {
            float a = colA[j], c = colB[j];
            a = fmaxf(a, __shfl_xor(a, 16)); a = fmaxf(a, __shfl_xor(a, 32));
            if (z == 2) { c = fmaxf(c, __shfl_xor(c, 16)); c = fmaxf(c, __shfl_xor(c, 32)); }
            if (quad == 0) {
                int n = nBase + nw + j * 16 + lr;
                int idx = (b * NH + (n >> 6)) * 64 + (n & 63);
                if (z == 1) atomicMax(sKb + idx, __float_as_int(a));
                else { atomicMax(vMx + idx, __float_as_int(a)); atomicMax(vNg + idx, __float_as_int(c)); }
            }
        }
    }
}

// O-projection GEMM, same BK=64 / B-direct structure, out row-major [M,N] in flag dtype.
__global__ __launch_bounds__(256) void gemm_o(
    const bf16* __restrict__ A, const bf16* __restrict__ W,
    const void* __restrict__ bias, void* __restrict__ out, const int* __restrict__ flagp)
{
    const int K = NE, N = NE;
    __shared__ __align__(16) bf16 As[128 * 64];
    int tid = threadIdx.x;
    int w = tid >> 6, l = tid & 63;
    int lr = l & 15, quad = l >> 4;
    int mBase = blockIdx.y * 128, nBase = blockIdx.x * 128;
    int mw = (w >> 1) * 64, nw = (w & 1) * 64;
    f32x4 acc[4][4] = {};

    int srow = w * 32 + (l >> 3);
    int scol = ((l & 7) ^ ((l >> 3) & 7)) * 8;
    const bf16* Ag = A + (size_t)(mBase + srow) * K + scol;
    bf16* AsW = As + (w * 32) * 64;
    const bf16* Wp = W + (size_t)(nBase + nw + lr) * K + quad * 8;

    for (int k0 = 0; k0 < K; k0 += 64) {
        #pragma unroll
        for (int c = 0; c < 4; c++)
            gll16(Ag + (size_t)(c * 8) * K + k0, AsW + (c * 8) * 64);
        short8 bfr[4][2];
        #pragma unroll
        for (int j = 0; j < 4; j++)
            #pragma unroll
            for (int h = 0; h < 2; h++)
                bfr[j][h] = *(const short8*)(Wp + (size_t)(j * 16) * K + k0 + h * 32);
        __syncthreads();
        #pragma unroll
        for (int i = 0; i < 4; i++) {
            #pragma unroll
            for (int h = 0; h < 2; h++) {
                short8 a8 = *(const short8*)(
                    As + (mw + i * 16 + lr) * 64 + (((h * 4 + quad) ^ (lr & 7)) * 8));
                #pragma unroll
                for (int j = 0; j < 4; j++)
                    acc[i][j] = __builtin_amdgcn_mfma_f32_16x16x32_bf16(
                        a8, bfr[j][h], acc[i][j], 0, 0, 0);
            }
        }
        __syncthreads();
    }

    const bool f32 = (*flagp != 0);
    #pragma unroll
    for (int i = 0; i < 4; i++) {
        #pragma unroll
        for (int j = 0; j < 4; j++) {
            int n = nBase + nw + j * 16 + lr;
            float bv = f32 ? ((const float*)bias)[n] : bitsbf16(((const short*)bias)[n]);
            #pragma unroll
            for (int r = 0; r < 4; r++) {
                int m = mBase + mw + i * 16 + quad * 4 + r;
                float vv = acc[i][j][r] + bv;
                if (f32) ((float*)out)[(size_t)m * N + n] = vv;
                else     ((bf16*)out)[(size_t)m * N + n] = (bf16)vv;
            }
        }
    }
}

// Merged: x<256 -> K smooth+per-token quant; else V per-channel quant.
__global__ __launch_bounds__(256) void quant_kv(
    bf16* __restrict__ Kb, bf16* __restrict__ Vt,
    const int* __restrict__ sKbits, const int* __restrict__ vMax, const int* __restrict__ vNeg)
{
    int bh = blockIdx.y;
    if (blockIdx.x < 256) {
        int t = blockIdx.x * 4 + (threadIdx.x >> 6);
        int l = threadIdx.x & 63;
        size_t idx = ((size_t)bh * NT + t) * ND + l;
        float s = fmaxf(__int_as_float(sKbits[bh * 64 + l]), 1e-5f);
        float x = (float)Kb[idx] / s;
        float mx = fmaxf(x, 0.f), mn = fminf(x, 0.f);
        #pragma unroll
        for (int off = 1; off < 64; off <<= 1) {
            mx = fmaxf(mx, __shfl_xor(mx, off));
            mn = fminf(mn, __shfl_xor(mn, off));
        }
        float sc = (mx - mn) * (1.f / 255.f);
        if (sc <= 0.f) sc = 1.f;
        float z = rintf(-mn / sc);
        float q = fminf(fmaxf(rintf(x / sc) + z, 0.f), 255.f);
        Kb[idx] = (bf16)(s * (sc * (q - z)));
    } else {
        int d = (blockIdx.x - 256) * 8 + (threadIdx.x >> 5);
        int c = (threadIdx.x & 31) * 8;
        float mx = __int_as_float(vMax[bh * 64 + d]);
        float mn = -__int_as_float(vNeg[bh * 64 + d]);
        float sc = (mx - mn) * (1.f / 255.f);
        if (sc <= 0.f) sc = 1.f;
        float z = rintf(-mn / sc);
        bf16* row = Vt + ((size_t)bh * ND + d) * NT;
        for (int seg = 0; seg < 4; seg++) {
            int off = seg * 256 + c;
            short8 v8 = *(const short8*)(row + off);
            #pragma unroll
            for (int k = 0; k < 8; k++) {
                float f = bitsbf16(v8[k]);
                float q = fminf(fmaxf(rintf(f / sc) + z, 0.f), 255.f);
                v8[k] = bf16bits(sc * (q - z));
            }
            *(short8*)(row + off) = v8;
        }
    }
}

// Flash-style causal attention, double-buffered XOR-swizzled LDS K/V staging (round-5, validated).
__global__ __launch_bounds__(256) void attn3(
    const bf16* __restrict__ Q, const bf16* __restrict__ K,
    const bf16* __restrict__ Vt, bf16* __restrict__ O)
{
    int bh = blockIdx.y;
    int b = bh >> 5, h = bh & 31;
    int qb = (int)gridDim.x - 1 - (int)blockIdx.x;   // heavy blocks first
    int qBase = qb * 64;
    int w = threadIdx.x >> 6, l = threadIdx.x & 63;
    int lr = l & 15, quad = l >> 4;
    int qRow = qBase + w * 16;

    __shared__ __align__(16) bf16 Ks[2][64 * 64];
    __shared__ __align__(16) bf16 Vs[2][64 * 64];
    __shared__ __align__(16) bf16 Psh[4][16 * 64];

    const bf16* Kbase = K + (size_t)bh * NT * ND;
    const bf16* Vbase = Vt + (size_t)bh * ND * NT;

    const bf16* Qp = Q + ((size_t)bh * NT + qRow + lr) * ND + quad * 8;
    short8 qf0 = *(const short8*)Qp;
    short8 qf1 = *(const short8*)(Qp + 32);

    f32x4 o[4] = {};
    float m_i[4], l_i[4];
    #pragma unroll
    for (int r = 0; r < 4; r++) { m_i[r] = -1e30f; l_i[r] = 0.f; }

    int nkt = qb + 1;
    int srow = w * 16 + (l >> 3);
    int scol = (((l & 7) ^ ((l >> 3) & 7))) * 8;

    auto stage = [&](int kt, int bufi) {
        int kc0 = kt * 64;
        #pragma unroll
        for (int c = 0; c < 2; c++) {
            gll16(Kbase + (size_t)(kc0 + srow + c * 8) * ND + scol,
                  &Ks[bufi][(w * 16 + c * 8) * 64]);
            gll16(Vbase + (size_t)(srow + c * 8) * NT + kc0 + scol,
                  &Vs[bufi][(w * 16 + c * 8) * 64]);
        }
    };
    stage(0, 0);

    int slot0 = (quad ^ (lr & 7)) * 8;
    int slot1 = ((quad ^ 4) ^ (lr & 7)) * 8;

    for (int kt = 0; kt < nkt; kt++) {
        __syncthreads();
        if (kt + 1 < nkt) stage(kt + 1, (kt + 1) & 1);
        const bf16* Kt = Ks[kt & 1];
        const bf16* Vv = Vs[kt & 1];
        int kc0 = kt * 64;

        f32x4 s[4] = {};
        #pragma unroll
        for (int nb = 0; nb < 4; nb++) {
            short8 b0 = *(const short8*)(Kt + (nb * 16 + lr) * 64 + slot0);
            short8 b1 = *(const short8*)(Kt + (nb * 16 + lr) * 64 + slot1);
            s[nb] = __builtin_amdgcn_mfma_f32_16x16x32_bf16(qf0, b0, s[nb], 0, 0, 0);
            s[nb] = __builtin_amdgcn_mfma_f32_16x16x32_bf16(qf1, b1, s[nb], 0, 0, 0);
        }

        int row0 = qRow + quad * 4;
        float rmax[4];
        #pragma unroll
        for (int r = 0; r < 4; r++) rmax[r] = -1e30f;
        if (kt == qb) {
            #pragma unroll
            for (int nb = 0; nb < 4; nb++) {
                int col = kc0 + nb * 16 + lr;
                #pragma unroll
                for (int r = 0; r < 4; r++) {
                    if (col > row0 + r) s[nb][r] = -1e30f;
                    rmax[r] = fmaxf(rmax[r], s[nb][r]);
                }
            }
        } else {
            #pragma unroll
            for (int nb = 0; nb < 4; nb++)
                #pragma unroll
                for (int r = 0; r < 4; r++)
                    rmax[r] = fmaxf(rmax[r], s[nb][r]);
        }
        #pragma unroll
        for (int off = 1; off < 16; off <<= 1)
            #pragma unroll
            for (int r = 0; r < 4; r++)
                rmax[r] = fmaxf(rmax[r], __shfl_xor(rmax[r], off));

        float alpha[4], rsum[4];
        #pragma unroll
        for (int r = 0; r < 4; r++) {
            float mn2 = fmaxf(m_i[r], rmax[r]);
            alpha[r] = __expf(m_i[r] - mn2);
            m_i[r] = mn2;
            rsum[r] = 0.f;
        }
        #pragma unroll
        for (int nb = 0; nb < 4; nb++) {
            int cb = nb * 2 + (lr >> 3), ci = lr & 7;
            #pragma unroll
            for (int r = 0; r < 4; r++) {
                float pp = __expf(s[nb][r] - m_i[r]);
                rsum[r] += pp;
                int row = quad * 4 + r;
                Psh[w][row * 64 + (cb ^ (row & 7)) * 8 + ci] = (bf16)pp;
            }
        }
        #pragma unroll
        for (int off = 1; off < 16; off <<= 1)
            #pragma unroll
            for (int r = 0; r < 4; r++)
                rsum[r] += __shfl_xor(rsum[r], off);
        #pragma unroll
        for (int r = 0; r < 4; r++) l_i[r] = l_i[r] * alpha[r] + rsum[r];
        #pragma unroll
        for (int f = 0; f < 4; f++)
            #pragma unroll
            for (int r = 0; r < 4; r++)
                o[f][r] *= alpha[r];

        __syncthreads();
        short8 p0 = *(const short8*)(&Psh[w][lr * 64 + slot0]);
        short8 p1 = *(const short8*)(&Psh[w][lr * 64 + slot1]);
        #pragma unroll
        for (int f = 0; f < 4; f++) {
            short8 v0 = *(const short8*)(Vv + (f * 16 + lr) * 64 + slot0);
            short8 v1 = *(const short8*)(Vv + (f * 16 + lr) * 64 + slot1);
            o[f] = __builtin_amdgcn_mfma_f32_16x16x32_bf16(p0, v0, o[f], 0, 0, 0);
            o[f] = __builtin_amdgcn_mfma_f32_16x16x32_bf16(p1, v1, o[f], 0, 0, 0);
        }
    }

    float inv[4];
    #pragma unroll
    for (int r = 0; r < 4; r++) inv[r] = 1.f / l_i[r];
    #pragma unroll
    for (int f = 0; f < 4; f++)
        #pragma unroll
        for (int r = 0; r < 4; r++) {
            int t = qRow + quad * 4 + r;
            int d = f * 16 + lr;
            O[((size_t)(b * NT + t)) * NE + h * ND + d] = (bf16)(o[f][r] * inv[r]);
        }
}

// ---------------- fallback path (round-3, validated; used if ws too small) ----------------
__device__ __forceinline__ void stage_tile(const void* __restrict__ src, bool f32,
                                           int rowBase, int k0, bf16* dst, int tid)
{
    const int K = NE;
    if (f32) {
        int r = tid >> 3;
        int c = (tid & 7) * 4;
        const float* p = (const float*)src + (size_t)(rowBase + r) * K + k0 + c;
        bf16* d = dst + r * 32 + c;
        #pragma unroll
        for (int i = 0; i < 4; i++) {
            f32x4 v = *(const f32x4*)(p + (size_t)(i * 32) * K);
            short4v o;
            o[0] = bf16bits(v[0]); o[1] = bf16bits(v[1]);
            o[2] = bf16bits(v[2]); o[3] = bf16bits(v[3]);
            *(short4v*)(d + i * 32 * 32) = o;
        }
    } else {
        int r = tid >> 2;
        int c = (tid & 3) * 8;
        const bf16* p = (const bf16*)src + (size_t)(rowBase + r) * K + k0 + c;
        bf16* d = dst + r * 32 + c;
        #pragma unroll
        for (int i = 0; i < 2; i++)
            *(short8*)(d + i * 64 * 32) = *(const short8*)(p + (size_t)(i * 64) * K);
    }
}

template<bool A_DYN, int MODE>
__global__ __launch_bounds__(256) void gemm_bt(
    const void* __restrict__ A, const void* __restrict__ W,
    const void* __restrict__ bias, float scale, void* __restrict__ out,
    const int* __restrict__ flagp)
{
    const int K = NE, N = NE;
    const bool f32 = (*flagp != 0);
    __shared__ __align__(16) bf16 As[128 * 32];
    __shared__ __align__(16) bf16 Ws[128 * 32];
    int tid = threadIdx.x;
    int w = tid >> 6, l = tid & 63;
    int lr = l & 15, quad = l >> 4;
    int mBase = blockIdx.y * 128;
    int nBase = blockIdx.x * 128;
    int mw = (w >> 1) * 64, nw = (w & 1) * 64;
    f32x4 acc[4][4] = {};
    for (int k0 = 0; k0 < K; k0 += 32) {
        stage_tile(A, A_DYN && f32, mBase, k0, As, tid);
        stage_tile(W, f32, nBase, k0, Ws, tid);
        __syncthreads();
        short8 af[4], bfr[4];
        #pragma unroll
        for (int i = 0; i < 4; i++)
            af[i] = *(const short8*)(As + (mw + i * 16 + lr) * 32 + quad * 8);
        #pragma unroll
        for (int j = 0; j < 4; j++)
            bfr[j] = *(const short8*)(Ws + (nw + j * 16 + lr) * 32 + quad * 8);
        #pragma unroll
        for (int i = 0; i < 4; i++)
            #pragma unroll
            for (int j = 0; j < 4; j++)
                acc[i][j] = __builtin_amdgcn_mfma_f32_16x16x32_bf16(
                    af[i], bfr[j], acc[i][j], 0, 0, 0);
        __syncthreads();
    }
    #pragma unroll
    for (int i = 0; i < 4; i++) {
        #pragma unroll
        for (int j = 0; j < 4; j++) {
            int n = nBase + nw + j * 16 + lr;
            float bv = f32 ? ((const float*)bias)[n] : bitsbf16(((const short*)bias)[n]);
            #pragma unroll
            for (int r = 0; r < 4; r++) {
                int m = mBase + mw + i * 16 + quad * 4 + r;
                float v = (acc[i][j][r] + bv) * scale;
                if (MODE == 0) {
                    if (f32) ((float*)out)[(size_t)m * N + n] = v;
                    else     ((bf16*)out)[(size_t)m * N + n] = (bf16)v;
                } else {
                    int b = m >> 10, t = m & (NT - 1);
                    int h = n >> 6, d = n & (ND - 1);
                    if (MODE == 1)
                        ((bf16*)out)[(((size_t)(b * NH + h)) * NT + t) * ND + d] = (bf16)v;
                    else
                        ((bf16*)out)[(((size_t)(b * NH + h)) * ND + d) * NT + t] = (bf16)v;
                }
            }
        }
    }
}

__global__ __launch_bounds__(256) void stats_k(
    const bf16* __restrict__ K, float* __restrict__ sK)
{
    int bh = blockIdx.x;
    int d = threadIdx.x & 63, tg = threadIdx.x >> 6;
    const bf16* Kp = K + (size_t)bh * NT * ND;
    float kabs = 0.f;
    for (int t = tg; t < NT; t += 4)
        kabs = fmaxf(kabs, fabsf((float)Kp[t * ND + d]));
    __shared__ float sh[4][64];
    sh[tg][d] = kabs;
    __syncthreads();
    if (threadIdx.x < 64) {
        kabs = fmaxf(fmaxf(sh[0][d], sh[1][d]), fmaxf(sh[2][d], sh[3][d]));
        sK[bh * 64 + d] = fmaxf(kabs, 1e-5f);
    }
}

__global__ __launch_bounds__(256) void stats_v(
    const bf16* __restrict__ Vt, float* __restrict__ vScale, float* __restrict__ vZero)
{
    int bh = blockIdx.x;
    int c = threadIdx.x >> 2;
    int seg = threadIdx.x & 3;
    const bf16* row = Vt + ((size_t)bh * ND + c) * NT + seg * 256;
    float vmax = 0.f, vmin = 0.f;
    for (int i = 0; i < 256; i += 8) {
        short8 v8 = *(const short8*)(row + i);
        for (int j = 0; j < 8; j++) {
            float f = bitsbf16(v8[j]);
            vmax = fmaxf(vmax, f);
            vmin = fminf(vmin, f);
        }
    }
    vmax = fmaxf(vmax, __shfl_xor(vmax, 1));
    vmax = fmaxf(vmax, __shfl_xor(vmax, 2));
    vmin = fminf(vmin, __shfl_xor(vmin, 1));
    vmin = fminf(vmin, __shfl_xor(vmin, 2));
    if (seg == 0) {
        float sc = (vmax - vmin) * (1.f / 255.f);
        if (sc <= 0.f) sc = 1.f;
        vScale[bh * 64 + c] = sc;
        vZero[bh * 64 + c] = rintf(-vmin / sc);
    }
}

__global__ __launch_bounds__(256) void quant_qk(
    bf16* __restrict__ Q, bf16* __restrict__ K, const float* __restrict__ sK)
{
    int bh = blockIdx.y;
    int t = blockIdx.x * 4 + (threadIdx.x >> 6);
    int l = threadIdx.x & 63;
    size_t idx = ((size_t)bh * NT + t) * ND + l;
    {
        float x = (float)Q[idx];
        float xmax = fmaxf(x, 0.f), xmin = fminf(x, 0.f);
        for (int off = 1; off < 64; off <<= 1) {
            xmax = fmaxf(xmax, __shfl_xor(xmax, off));
            xmin = fminf(xmin, __shfl_xor(xmin, off));
        }
        float sc = (xmax - xmin) * (1.f / 255.f);
        if (sc <= 0.f) sc = 1.f;
        float z = rintf(-xmin / sc);
        float q = fminf(fmaxf(rintf(x / sc) + z, 0.f), 255.f);
        Q[idx] = (bf16)(sc * (q - z));
    }
    {
        float s = sK[bh * 64 + l];
        float x = (float)K[idx] / s;
        float xmax = fmaxf(x, 0.f), xmin = fminf(x, 0.f);
        for (int off = 1; off < 64; off <<= 1) {
            xmax = fmaxf(xmax, __shfl_xor(xmax, off));
            xmin = fminf(xmin, __shfl_xor(xmin, off));
        }
        float sc = (xmax - xmin) * (1.f / 255.f);
        if (sc <= 0.f) sc = 1.f;
        float z = rintf(-xmin / sc);
        float q = fminf(fmaxf(rintf(x / sc) + z, 0.f), 255.f);
        K[idx] = (bf16)(s * (sc * (q - z)));
    }
}

__global__ __launch_bounds__(256) void quant_v_old(
    bf16* __restrict__ Vt,
    const float* __restrict__ vScale, const float* __restrict__ vZero)
{
    int bh = blockIdx.y, d = blockIdx.x;
    float sc = vScale[bh * 64 + d], z = vZero[bh * 64 + d];
    bf16* row = Vt + ((size_t)bh * ND + d) * NT;
    for (int t = threadIdx.x; t < NT; t += 256) {
        float v = (float)row[t];
        float q = fminf(fmaxf(rintf(v / sc) + z, 0.f), 255.f);
        row[t] = (bf16)(sc * (q - z));
    }
}

extern "C" void kernel_launch(void* const* d_in, const int* in_sizes, int n_in,
                              void* d_out, int out_size, void* d_ws, size_t ws_size,
                              hipStream_t stream)
{
    (void)in_sizes; (void)n_in; (void)out_size;
    const void* hs = d_in[0];
    const void* wq = d_in[1];
    const void* bq = d_in[2];
    const void* wk = d_in[3];
    const void* bk = d_in[4];
    const void* wv = d_in[5];
    const void* bv = d_in[6];
    const void* wo = d_in[7];
    const void* bo = d_in[8];
    // d_in[9] = attention_mask: exact causal, applied analytically.

    const size_t qkvE = (size_t)NBH * NT * ND;       // 8.39M elems
    const size_t qkvB = qkvE * 2;                    // 16.78 MB
    const size_t wBy  = (size_t)NE * NE * 2;         // 8.39 MB
    const size_t statB = 3 * (size_t)NBH * ND * 4;   // 96 KB
    const size_t needFast = 4 * qkvB + 4 * wBy + statB + 256;

    dim3 blk(256);
    dim3 gG(NE / 128, (NB * NT) / 128);
    const float scaling = 0.125f;  // 64^-0.5

    if (ws_size >= needFast) {
        char* p = (char*)d_ws;
        bf16* Qb  = (bf16*)p; p += qkvB;
        bf16* Kb  = (bf16*)p; p += qkvB;
        bf16* Vt  = (bf16*)p; p += qkvB;
        bf16* hsB = (bf16*)p; p += qkvB;             // reused as Ab after QKV
        bf16* wqB = (bf16*)p; p += wBy;
        bf16* wkB = (bf16*)p; p += wBy;
        bf16* wvB = (bf16*)p; p += wBy;
        bf16* woB = (bf16*)p; p += wBy;
        int* sKb = (int*)p;
        int* vMx = sKb + NBH * ND;
        int* vNg = vMx + NBH * ND;
        int* flag = vNg + NBH * ND;
        bf16* Ab = hsB;

        detect_dtype<<<dim3(1), dim3(64), 0, stream>>>((const unsigned short*)wq, flag);
        hipMemsetAsync(sKb, 0, statB, stream);
        conv_all<<<dim3(4096 + 4 * 2048), blk, 0, stream>>>(
            hs, wq, wk, wv, wo, hsB, wqB, wkB, wvB, woB, flag);
        gemm_qkv<<<dim3(NE / 128, (NB * NT) / 128, 3), blk, 0, stream>>>(
            hsB, wqB, wkB, wvB, bq, bk, bv, Qb, Kb, Vt, flag, sKb, vMx, vNg);
        quant_kv<<<dim3(256 + ND / 8, NBH), blk, 0, stream>>>(Kb, Vt, sKb, vMx, vNg);
        attn3<<<dim3(NT / 64, NBH), blk, 0, stream>>>(Qb, Kb, Vt, Ab);
        gemm_o<<<gG, blk, 0, stream>>>(Ab, woB, bo, d_out, flag);
    } else {
        bf16* Qb = (bf16*)d_ws;
        bf16* Kb = Qb + qkvE;
        bf16* Vt = Kb + qkvE;
        bf16* Ab = Vt + qkvE;
        float* sK  = (float*)(Ab + qkvE);
        float* vSc = sK + NBH * ND;
        float* vZp = vSc + NBH * ND;
        int*   flag = (int*)(vZp + NBH * ND);

        detect_dtype<<<dim3(1), dim3(64), 0, stream>>>((const unsigned short*)wq, flag);
        gemm_bt<true, 1><<<gG, blk, 0, stream>>>(hs, wq, bq, scaling, Qb, flag);
        gemm_bt<true, 1><<<gG, blk, 0, stream>>>(hs, wk, bk, 1.0f, Kb, flag);
        gemm_bt<true, 2><<<gG, blk, 0, stream>>>(hs, wv, bv, 1.0f, Vt, flag);
        stats_k<<<dim3(NBH), blk, 0, stream>>>(Kb, sK);
        stats_v<<<dim3(NBH), blk, 0, stream>>>(Vt, vSc, vZp);
        quant_qk<<<dim3(NT / 4, NBH), blk, 0, stream>>>(Qb, Kb, sK);
        quant_v_old<<<dim3(ND, NBH), blk, 0, stream>>>(Vt, vSc, vZp);
        attn3<<<dim3(NT / 64, NBH), blk, 0, stream>>>(Qb, Kb, Vt, Ab);
        gemm_bt<false, 0><<<gG, blk, 0, stream>>>(Ab, wo, bo, 1.0f, d_out, flag);
    }
}